// Round 4
// baseline (338.945 us; speedup 1.0000x reference)
//
#include <hip/hip_runtime.h>

#define C_CLS 50
#define B_TR 8
#define T_FULL 600
#define T_USE 500
#define N_NEU 30000
#define NG 469            // ceil(30000/64) 64-bit groups per row
#define BSTRIDE 472       // u64 stride per class bitset row (padded)
#define NBINS 16
#define EPS 1e-7

__device__ __constant__ int d_bins[NBINS] = {1,1,2,3,4,6,9,13,18,26,38,55,78,113,162,234};

// ws layout (bytes):
//   flags        @ 0      int[8]
//   ncls         @ 256    int[8]
//   cls_of_trial @ 512    int[8*64]
//   fanos        @ 4096   float[16]
//   bits         @ 8192   u64[50*472]   (188,800 B)
//   selected     @ 200704 float[50*500] (100,000 B)  -> total ~295 KB

// ---------------------------------------------------------------------------
// init: zero detection flags and per-trial class counters (ws is poisoned
// 0xAA once and never re-poisoned -> must init every launch).
// ---------------------------------------------------------------------------
__global__ void init_kernel(int* flags, int* ncls) {
    int i = threadIdx.x;
    if (i < 8) { flags[i] = 0; ncls[i] = 0; }
}

// ---------------------------------------------------------------------------
// detect: classify the bool sel_mask buffer encoding.
// modes: 0=int32, 1=uint8, 2=float32, 3=int64, 4=float64
// ---------------------------------------------------------------------------
__global__ void detect_mode_kernel(const unsigned int* __restrict__ w, int* flags) {
    const int nwords = C_CLS * N_NEU / 4; // smallest possible buffer in words
    int stride = gridDim.x * blockDim.x;
    int fF = 0, fB = 0, fO = 0, fD = 0;
    for (int i = blockIdx.x * blockDim.x + threadIdx.x; i < nwords; i += stride) {
        unsigned int v = w[i];
        if (v == 0u) continue;
        if (v == 0x3F800000u) fF = 1;
        else if (v == 0x3FF00000u && (i & 1)) fD = 1;
        else {
            unsigned int b0 = v & 0xFFu, b1 = (v >> 8) & 0xFFu,
                         b2 = (v >> 16) & 0xFFu, b3 = (v >> 24) & 0xFFu;
            bool byteOK = (b0 <= 1u) && (b1 <= 1u) && (b2 <= 1u) && (b3 <= 1u);
            if (byteOK && v != 1u) fB = 1;
        }
        if (i & 1) fO = 1;
    }
    if (fF) atomicOr(&flags[0], 1);
    if (fB) atomicOr(&flags[1], 1);
    if (fO) atomicOr(&flags[2], 1);
    if (fD) atomicOr(&flags[3], 1);
}

__device__ __forceinline__ int mode_from_flags(const int* flags) {
    if (flags[0]) return 2;        // float32 pattern
    if (flags[3]) return 4;        // float64 pattern
    if (flags[1]) return 1;        // packed bytes
    if (flags[2]) return 0;        // 0/1 words at odd positions -> int32
    return 3;                      // 0/1 only at even words -> int64
}

// ---------------------------------------------------------------------------
// build_bits: per-class neuron bitset, bit i of word g = mask[c][g*64+i].
// One wave per (class, group-stride). Built with __ballot so the bit<->lane
// correspondence exactly matches the streaming kernel's ballot.
// ---------------------------------------------------------------------------
__global__ void build_bits_kernel(const void* mask, const int* flags,
                                  unsigned long long* bits) {
    int c = blockIdx.x;
    int lane = threadIdx.x;            // 64 threads = 1 wave
    int mode = mode_from_flags(flags);
    for (int g = blockIdx.y; g < NG; g += gridDim.y) {
        int n = g * 64 + lane;
        bool sel = false;
        if (n < N_NEU) {
            long long e = (long long)c * N_NEU + n;
            switch (mode) {
                case 0:  sel = ((const int*)mask)[e] != 0; break;
                case 1:  sel = ((const unsigned char*)mask)[e] != 0; break;
                case 2:  sel = ((const float*)mask)[e] != 0.0f; break;
                case 3:  sel = ((const long long*)mask)[e] != 0LL; break;
                default: sel = ((const double*)mask)[e] != 0.0; break;
            }
        }
        unsigned long long w = __ballot(sel);
        if (lane == 0) bits[(long long)c * BSTRIDE + g] = w;
    }
}

// ---------------------------------------------------------------------------
// trial_cls: invert sample_trials -> per-trial class lists. Order within a
// list is nondeterministic but per-class results don't depend on it.
// ---------------------------------------------------------------------------
__global__ void trial_cls_kernel(const int* __restrict__ trials,
                                 int* ncls, int* cls_of_trial) {
    int c = threadIdx.x;
    if (c < C_CLS) {
        int b = trials[c];
        int p = atomicAdd(&ncls[b], 1);
        cls_of_trial[b * 64 + p] = c;
    }
}

// ---------------------------------------------------------------------------
// stream: one block per (trial,t) row. 4 waves stream the 30000-float row
// coalescedly; ballot packs 64 spikes (exact 0/1) into a u64; lane j < ncls
// ANDs with class j's bitset word and popcounts. Exactly one block writes
// each selected[c][t] -> no atomics, no pre-zero.
// ---------------------------------------------------------------------------
__global__ void __launch_bounds__(256)
stream_kernel(const float* __restrict__ spikes,
              const int* __restrict__ ncls,
              const int* __restrict__ cls_of_trial,
              const unsigned long long* __restrict__ bits,
              float* __restrict__ selected) {
    int bt = blockIdx.x;
    int b = bt / T_USE;
    int t = bt - b * T_USE;
    int nc = ncls[b];
    if (nc == 0) return;
    int lane = threadIdx.x & 63;
    int wid = threadIdx.x >> 6;
    int myc = cls_of_trial[b * 64 + (lane < nc ? lane : 0)];
    const unsigned long long* __restrict__ bp = bits + (long long)myc * BSTRIDE;
    const float* __restrict__ row = spikes + ((long long)b * T_FULL + t) * N_NEU;
    int acc = 0;
    int g0 = wid * 118;
    int g1 = g0 + 118; if (g1 > NG) g1 = NG;
#pragma unroll 4
    for (int g = g0; g < g1; ++g) {
        int n = g * 64 + lane;
        int n2 = n < N_NEU ? n : N_NEU - 1;
        float v = row[n2] * (n < N_NEU ? 1.0f : 0.0f);
        unsigned long long bm = __ballot(v != 0.0f);
        if (lane < nc) acc += __popcll(bm & bp[g]);
    }
    __shared__ int sacc[4][64];
    sacc[wid][lane] = acc;
    __syncthreads();
    if (wid == 0 && lane < nc) {
        int s = sacc[0][lane] + sacc[1][lane] + sacc[2][lane] + sacc[3][lane];
        selected[myc * T_USE + t] = (float)s;
    }
}

// ---------------------------------------------------------------------------
// fano: per-bin Fano factor averaged over classes (lane per class, double
// accumulators — counts are small exact integers).
// ---------------------------------------------------------------------------
__global__ void fano_kernel(const float* __restrict__ selected,
                            float* __restrict__ fanos) {
    int bin = blockIdx.x;
    int b = d_bins[bin];
    int nb = T_USE / b;
    int c = threadIdx.x;
    float fano = 0.f;
    if (c < C_CLS) {
        const float* row = selected + c * T_USE;
        double s1 = 0.0, s2 = 0.0;
        for (int i = 0; i < nb; ++i) {
            float cs = 0.f;
            int base = i * b;
            for (int j = 0; j < b; ++j) cs += row[base + j];
            s1 += cs;
            s2 += (double)cs * (double)cs;
        }
        double mean = s1 / nb;
        double var = s2 / nb - mean * mean;
        if (var < 0.0) var = 0.0;
        double m = mean > EPS ? mean : EPS;
        fano = (float)(var / m);
    }
    for (int off = 32; off > 0; off >>= 1) fano += __shfl_down(fano, off);
    if (threadIdx.x == 0) fanos[bin] = fano / (float)C_CLS;
}

// ---------------------------------------------------------------------------
// loss: SYNC_COST * mean((exp - fano)^2)
// ---------------------------------------------------------------------------
__global__ void loss_kernel(const float* __restrict__ fanos,
                            const float* __restrict__ exp_fanos,
                            float* __restrict__ out) {
    int t = threadIdx.x;
    float sq = 0.f;
    if (t < NBINS) {
        float d = exp_fanos[t] - fanos[t];
        sq = d * d;
    }
    for (int off = 32; off > 0; off >>= 1) sq += __shfl_down(sq, off);
    if (t == 0) out[0] = 10.0f * sq / (float)NBINS;
}

extern "C" void kernel_launch(void* const* d_in, const int* in_sizes, int n_in,
                              void* d_out, int out_size, void* d_ws, size_t ws_size,
                              hipStream_t stream) {
    const float* spikes    = (const float*)d_in[0];
    const float* exp_fanos = (const float*)d_in[1];
    const int*   trials    = (const int*)d_in[2];
    const void*  mask      = d_in[3];
    float* out = (float*)d_out;

    char* ws = (char*)d_ws;
    int*   flags   = (int*)(ws + 0);
    int*   ncls    = (int*)(ws + 256);
    int*   clsofb  = (int*)(ws + 512);
    float* fanos   = (float*)(ws + 4096);
    unsigned long long* bits = (unsigned long long*)(ws + 8192);
    float* selected = (float*)(ws + 200704);

    init_kernel<<<1, 64, 0, stream>>>(flags, ncls);
    detect_mode_kernel<<<512, 256, 0, stream>>>((const unsigned int*)mask, flags);
    build_bits_kernel<<<dim3(C_CLS, 8), 64, 0, stream>>>(mask, flags, bits);
    trial_cls_kernel<<<1, 64, 0, stream>>>(trials, ncls, clsofb);
    stream_kernel<<<B_TR * T_USE, 256, 0, stream>>>(spikes, ncls, clsofb, bits, selected);
    fano_kernel<<<NBINS, 64, 0, stream>>>(selected, fanos);
    loss_kernel<<<1, 64, 0, stream>>>(fanos, exp_fanos, out);
}

// Round 5
// 262.148 us; speedup vs baseline: 1.2930x; 1.2930x over previous
//
#include <hip/hip_runtime.h>

#define C_CLS 50
#define B_TR 8
#define T_FULL 600
#define T_USE 500
#define N_NEU 30000
#define NGRP 118          // ceil(30000/256) groups of 256 neurons
#define WPC 472           // u64 words per class = NGRP*4 (16B aligned rows)
#define NBINS 16
#define EPS 1e-7

__device__ __constant__ int d_bins[NBINS] = {1,1,2,3,4,6,9,13,18,26,38,55,78,113,162,234};

// ws layout (bytes):
//   flags        @ 0      int[8]
//   ncls         @ 256    int[8]
//   cls_of_trial @ 512    int[8*64]
//   bits         @ 8192   u64[50*472] (188,800 B; rows 3776 B, 16B aligned)
//   selected     @ 200704 float[50*500]

// ---------------------------------------------------------------------------
// init_tc: one wave. Zero detect flags; invert sample_trials into per-trial
// class lists via ballot (deterministic: position = popcount of lower lanes).
// ---------------------------------------------------------------------------
__global__ void init_tc_kernel(const int* __restrict__ trials, int* flags,
                               int* ncls, int* cls_of_trial) {
    int lane = threadIdx.x; // 64 threads
    if (lane < 8) flags[lane] = 0;
    int b = (lane < C_CLS) ? trials[lane] : -1;
    for (int bb = 0; bb < B_TR; ++bb) {
        unsigned long long m = __ballot(b == bb);
        if (b == bb) {
            int pos = __popcll(m & ((1ull << lane) - 1ull));
            cls_of_trial[bb * 64 + pos] = lane;
        }
        if (lane == 0) ncls[bb] = __popcll(m);
    }
}

// ---------------------------------------------------------------------------
// detect: classify the bool sel_mask buffer encoding.
// modes: 0=int32, 1=uint8, 2=float32, 3=int64, 4=float64
// ---------------------------------------------------------------------------
__global__ void detect_mode_kernel(const unsigned int* __restrict__ w, int* flags) {
    const int nwords = C_CLS * N_NEU / 4; // smallest possible buffer in words
    int stride = gridDim.x * blockDim.x;
    int fF = 0, fB = 0, fO = 0, fD = 0;
    for (int i = blockIdx.x * blockDim.x + threadIdx.x; i < nwords; i += stride) {
        unsigned int v = w[i];
        if (v == 0u) continue;
        if (v == 0x3F800000u) fF = 1;
        else if (v == 0x3FF00000u && (i & 1)) fD = 1;
        else {
            unsigned int b0 = v & 0xFFu, b1 = (v >> 8) & 0xFFu,
                         b2 = (v >> 16) & 0xFFu, b3 = (v >> 24) & 0xFFu;
            bool byteOK = (b0 <= 1u) && (b1 <= 1u) && (b2 <= 1u) && (b3 <= 1u);
            if (byteOK && v != 1u) fB = 1;
        }
        if (i & 1) fO = 1;
    }
    if (fF) atomicOr(&flags[0], 1);
    if (fB) atomicOr(&flags[1], 1);
    if (fO) atomicOr(&flags[2], 1);
    if (fD) atomicOr(&flags[3], 1);
}

__device__ __forceinline__ int mode_from_flags(const int* flags) {
    if (flags[0]) return 2;
    if (flags[3]) return 4;
    if (flags[1]) return 1;
    if (flags[2]) return 0;
    return 3;
}

__device__ __forceinline__ bool load_sel(const void* mask, int mode, long long e) {
    switch (mode) {
        case 0:  return ((const int*)mask)[e] != 0;
        case 1:  return ((const unsigned char*)mask)[e] != 0;
        case 2:  return ((const float*)mask)[e] != 0.0f;
        case 3:  return ((const long long*)mask)[e] != 0LL;
        default: return ((const double*)mask)[e] != 0.0;
    }
}

// ---------------------------------------------------------------------------
// build_bits: class bitsets in INTERLEAVED order matching the float4 ballot:
// word (g,k) bit l = mask[c][g*256 + l*4 + k], stored at bits[c*WPC + g*4 + k].
// OOB bits are 0, which also masks ballot garbage from clamped loads.
// ---------------------------------------------------------------------------
__global__ void build_bits_kernel(const void* mask, const int* flags,
                                  unsigned long long* bits) {
    int c = blockIdx.x;
    int lane = threadIdx.x; // 64 = 1 wave
    int mode = mode_from_flags(flags);
    for (int g = blockIdx.y; g < NGRP; g += gridDim.y) {
        int base = g * 256 + lane * 4;
        long long e = (long long)c * N_NEU + base;
        bool s0 = (base + 0 < N_NEU) && load_sel(mask, mode, e + 0);
        bool s1 = (base + 1 < N_NEU) && load_sel(mask, mode, e + 1);
        bool s2 = (base + 2 < N_NEU) && load_sel(mask, mode, e + 2);
        bool s3 = (base + 3 < N_NEU) && load_sel(mask, mode, e + 3);
        unsigned long long w0 = __ballot(s0);
        unsigned long long w1 = __ballot(s1);
        unsigned long long w2 = __ballot(s2);
        unsigned long long w3 = __ballot(s3);
        if (lane == 0) {
            long long o = (long long)c * WPC + g * 4;
            bits[o + 0] = w0; bits[o + 1] = w1;
            bits[o + 2] = w2; bits[o + 3] = w3;
        }
    }
}

// ---------------------------------------------------------------------------
// stream: one block per (trial,t) row. Each lane loads float4 (16B, 1KB/wave
// per instr), 2x unrolled -> >=2 independent HBM loads in flight per wave.
// 4 ballots per float4; lane j<nc popcounts against class j's bitset words
// (ulonglong2 loads, L2-resident). Exactly one block writes each
// selected[c][t] -> no atomics, no pre-zero, deterministic exact counts.
// ---------------------------------------------------------------------------
__global__ void __launch_bounds__(256)
stream_kernel(const float* __restrict__ spikes,
              const int* __restrict__ ncls,
              const int* __restrict__ cls_of_trial,
              const unsigned long long* __restrict__ bits,
              float* __restrict__ selected) {
    int bt = blockIdx.x;
    int b = bt / T_USE;
    int t = bt - b * T_USE;
    int nc = ncls[b];
    if (nc == 0) return;
    int lane = threadIdx.x & 63;
    int wid = threadIdx.x >> 6;
    int myc = cls_of_trial[b * 64 + (lane < nc ? lane : 0)];
    const ulonglong2* __restrict__ bp2 =
        (const ulonglong2*)(bits + (long long)myc * WPC);
    const float4* __restrict__ row4 =
        (const float4*)(spikes + ((long long)b * T_FULL + t) * N_NEU);
    // wave g-ranges: 30,30,30,28 (all even -> pairs complete)
    int g0 = wid * 30;
    int g1 = g0 + 30; if (g1 > NGRP) g1 = NGRP;
    int acc = 0;
    for (int g = g0; g < g1; g += 2) {
        int ia = g * 64 + lane;       if (ia > 7499) ia = 7499;
        int ib = (g + 1) * 64 + lane; if (ib > 7499) ib = 7499;
        float4 va = row4[ia];
        float4 vb = row4[ib];
        ulonglong2 wa0 = bp2[g * 2 + 0];
        ulonglong2 wa1 = bp2[g * 2 + 1];
        ulonglong2 wb0 = bp2[g * 2 + 2];
        ulonglong2 wb1 = bp2[g * 2 + 3];
        unsigned long long a0 = __ballot(va.x != 0.0f);
        unsigned long long a1 = __ballot(va.y != 0.0f);
        unsigned long long a2 = __ballot(va.z != 0.0f);
        unsigned long long a3 = __ballot(va.w != 0.0f);
        unsigned long long c0 = __ballot(vb.x != 0.0f);
        unsigned long long c1 = __ballot(vb.y != 0.0f);
        unsigned long long c2 = __ballot(vb.z != 0.0f);
        unsigned long long c3 = __ballot(vb.w != 0.0f);
        if (lane < nc) {
            acc += __popcll(a0 & wa0.x) + __popcll(a1 & wa0.y)
                 + __popcll(a2 & wa1.x) + __popcll(a3 & wa1.y);
            acc += __popcll(c0 & wb0.x) + __popcll(c1 & wb0.y)
                 + __popcll(c2 & wb1.x) + __popcll(c3 & wb1.y);
        }
    }
    __shared__ int sacc[4][64];
    sacc[wid][lane] = acc;
    __syncthreads();
    if (wid == 0 && lane < nc) {
        int s = sacc[0][lane] + sacc[1][lane] + sacc[2][lane] + sacc[3][lane];
        selected[myc * T_USE + t] = (float)s;
    }
}

// ---------------------------------------------------------------------------
// fano_loss: one block, 16 waves. Wave w = bin w (lane per class, double
// accumulators — counts are small exact integers). Then wave 0 does the MSE.
// ---------------------------------------------------------------------------
__global__ void __launch_bounds__(1024)
fano_loss_kernel(const float* __restrict__ selected,
                 const float* __restrict__ exp_fanos,
                 float* __restrict__ out) {
    __shared__ float sf[NBINS];
    int wid = threadIdx.x >> 6;
    int lane = threadIdx.x & 63;
    int b = d_bins[wid];
    int nb = T_USE / b;
    float fano = 0.f;
    if (lane < C_CLS) {
        const float* row = selected + lane * T_USE;
        double s1 = 0.0, s2 = 0.0;
        for (int i = 0; i < nb; ++i) {
            float cs = 0.f;
            int base = i * b;
            for (int j = 0; j < b; ++j) cs += row[base + j];
            s1 += cs;
            s2 += (double)cs * (double)cs;
        }
        double mean = s1 / nb;
        double var = s2 / nb - mean * mean;
        if (var < 0.0) var = 0.0;
        double m = mean > EPS ? mean : EPS;
        fano = (float)(var / m);
    }
    for (int off = 32; off > 0; off >>= 1) fano += __shfl_down(fano, off);
    if (lane == 0) sf[wid] = fano / (float)C_CLS;
    __syncthreads();
    if (wid == 0) {
        float sq = 0.f;
        if (lane < NBINS) {
            float d = exp_fanos[lane] - sf[lane];
            sq = d * d;
        }
        for (int off = 32; off > 0; off >>= 1) sq += __shfl_down(sq, off);
        if (lane == 0) out[0] = 10.0f * sq / (float)NBINS;
    }
}

extern "C" void kernel_launch(void* const* d_in, const int* in_sizes, int n_in,
                              void* d_out, int out_size, void* d_ws, size_t ws_size,
                              hipStream_t stream) {
    const float* spikes    = (const float*)d_in[0];
    const float* exp_fanos = (const float*)d_in[1];
    const int*   trials    = (const int*)d_in[2];
    const void*  mask      = d_in[3];
    float* out = (float*)d_out;

    char* ws = (char*)d_ws;
    int*   flags   = (int*)(ws + 0);
    int*   ncls    = (int*)(ws + 256);
    int*   clsofb  = (int*)(ws + 512);
    unsigned long long* bits = (unsigned long long*)(ws + 8192);
    float* selected = (float*)(ws + 200704);

    init_tc_kernel<<<1, 64, 0, stream>>>(trials, flags, ncls, clsofb);
    detect_mode_kernel<<<256, 256, 0, stream>>>((const unsigned int*)mask, flags);
    build_bits_kernel<<<dim3(C_CLS, 8), 64, 0, stream>>>(mask, flags, bits);
    stream_kernel<<<B_TR * T_USE, 256, 0, stream>>>(spikes, ncls, clsofb, bits, selected);
    fano_loss_kernel<<<1, 1024, 0, stream>>>(selected, exp_fanos, out);
}

// Round 6
// 184.003 us; speedup vs baseline: 1.8421x; 1.4247x over previous
//
#include <hip/hip_runtime.h>

#define C_CLS 50
#define B_TR 8
#define T_FULL 600
#define T_USE 500
#define N_NEU 30000
#define NGRP 118          // ceil(30000/256) groups of 256 neurons
#define NGRP_PAD 120      // padded to a multiple of 4 (quad iteration)
#define WPC 480           // u64 words per class = NGRP_PAD*4
#define NQUAD 30          // NGRP_PAD/4
#define NBINS 16
#define EPS 1e-7
#define LDS_STRIDE 501    // floats; odd -> conflict-free lane-per-class reads

__device__ __constant__ int d_bins[NBINS] = {1,1,2,3,4,6,9,13,18,26,38,55,78,113,162,234};

// ws layout (bytes):
//   flags        @ 0      int[8]
//   ncls         @ 256    int[8]
//   cls_of_trial @ 512    int[8*64]
//   bits         @ 8192   u64[50*480] (192,000 B; rows 3840 B, 16B aligned)
//   selected     @ 204800 float[50*500] (100,000 B)

// ---------------------------------------------------------------------------
// init_tc: one wave. Zero detect flags; invert sample_trials into per-trial
// class lists via ballot (deterministic: position = popcount of lower lanes).
// ---------------------------------------------------------------------------
__global__ void init_tc_kernel(const int* __restrict__ trials, int* flags,
                               int* ncls, int* cls_of_trial) {
    int lane = threadIdx.x; // 64 threads
    if (lane < 8) flags[lane] = 0;
    int b = (lane < C_CLS) ? trials[lane] : -1;
    for (int bb = 0; bb < B_TR; ++bb) {
        unsigned long long m = __ballot(b == bb);
        if (b == bb) {
            int pos = __popcll(m & ((1ull << lane) - 1ull));
            cls_of_trial[bb * 64 + pos] = lane;
        }
        if (lane == 0) ncls[bb] = __popcll(m);
    }
}

// ---------------------------------------------------------------------------
// detect: classify the bool sel_mask buffer encoding.
// modes: 0=int32, 1=uint8, 2=float32, 3=int64, 4=float64
// ---------------------------------------------------------------------------
__global__ void detect_mode_kernel(const unsigned int* __restrict__ w, int* flags) {
    const int nwords = C_CLS * N_NEU / 4; // smallest possible buffer in words
    int stride = gridDim.x * blockDim.x;
    int fF = 0, fB = 0, fO = 0, fD = 0;
    for (int i = blockIdx.x * blockDim.x + threadIdx.x; i < nwords; i += stride) {
        unsigned int v = w[i];
        if (v == 0u) continue;
        if (v == 0x3F800000u) fF = 1;
        else if (v == 0x3FF00000u && (i & 1)) fD = 1;
        else {
            unsigned int b0 = v & 0xFFu, b1 = (v >> 8) & 0xFFu,
                         b2 = (v >> 16) & 0xFFu, b3 = (v >> 24) & 0xFFu;
            bool byteOK = (b0 <= 1u) && (b1 <= 1u) && (b2 <= 1u) && (b3 <= 1u);
            if (byteOK && v != 1u) fB = 1;
        }
        if (i & 1) fO = 1;
    }
    if (fF) atomicOr(&flags[0], 1);
    if (fB) atomicOr(&flags[1], 1);
    if (fO) atomicOr(&flags[2], 1);
    if (fD) atomicOr(&flags[3], 1);
}

__device__ __forceinline__ int mode_from_flags(const int* flags) {
    if (flags[0]) return 2;
    if (flags[3]) return 4;
    if (flags[1]) return 1;
    if (flags[2]) return 0;
    return 3;
}

__device__ __forceinline__ bool load_sel(const void* mask, int mode, long long e) {
    switch (mode) {
        case 0:  return ((const int*)mask)[e] != 0;
        case 1:  return ((const unsigned char*)mask)[e] != 0;
        case 2:  return ((const float*)mask)[e] != 0.0f;
        case 3:  return ((const long long*)mask)[e] != 0LL;
        default: return ((const double*)mask)[e] != 0.0;
    }
}

// ---------------------------------------------------------------------------
// build_bits: class bitsets in INTERLEAVED order matching the float4 ballot:
// word (g,k) bit l = mask[c][g*256 + l*4 + k] at bits[c*WPC + g*4 + k].
// Groups 118,119 (padding) get all-zero words -> they auto-mask the stream
// kernel's clamped duplicate loads.
// ---------------------------------------------------------------------------
__global__ void build_bits_kernel(const void* mask, const int* flags,
                                  unsigned long long* bits) {
    int c = blockIdx.x;
    int lane = threadIdx.x; // 64 = 1 wave
    int mode = mode_from_flags(flags);
    for (int g = blockIdx.y; g < NGRP_PAD; g += gridDim.y) {
        int base = g * 256 + lane * 4;
        long long e = (long long)c * N_NEU + base;
        bool s0 = (base + 0 < N_NEU) && load_sel(mask, mode, e + 0);
        bool s1 = (base + 1 < N_NEU) && load_sel(mask, mode, e + 1);
        bool s2 = (base + 2 < N_NEU) && load_sel(mask, mode, e + 2);
        bool s3 = (base + 3 < N_NEU) && load_sel(mask, mode, e + 3);
        unsigned long long w0 = __ballot(s0);
        unsigned long long w1 = __ballot(s1);
        unsigned long long w2 = __ballot(s2);
        unsigned long long w3 = __ballot(s3);
        if (lane == 0) {
            long long o = (long long)c * WPC + g * 4;
            bits[o + 0] = w0; bits[o + 1] = w1;
            bits[o + 2] = w2; bits[o + 3] = w3;
        }
    }
}

// ---------------------------------------------------------------------------
// stream: one block per (trial,t) row. Per iteration a wave processes a QUAD
// of 4 groups: 4 independent float4 spike loads (64B/lane in flight) + 8
// ulonglong2 bitset loads issued up front, then 16 ballots + popcounts.
// No lane<nc branch in the hot loop (junk lanes compute dead values).
// Exactly one block writes each selected[c][t] -> deterministic, no atomics.
// ---------------------------------------------------------------------------
__global__ void __launch_bounds__(256)
stream_kernel(const float* __restrict__ spikes,
              const int* __restrict__ ncls,
              const int* __restrict__ cls_of_trial,
              const unsigned long long* __restrict__ bits,
              float* __restrict__ selected) {
    int bt = blockIdx.x;
    int b = bt / T_USE;
    int t = bt - b * T_USE;
    int nc = ncls[b];
    if (nc == 0) return;
    int lane = threadIdx.x & 63;
    int wid = threadIdx.x >> 6;
    int myc = cls_of_trial[b * 64 + (lane < nc ? lane : 0)];
    const ulonglong2* __restrict__ bp2 = (const ulonglong2*)bits;
    long long base2 = (long long)myc * (WPC / 2);
    const float4* __restrict__ row4 =
        (const float4*)(spikes + ((long long)b * T_FULL + t) * N_NEU);
    // quads split 7/8/7/8 across the 4 waves
    int q0 = (wid * 15) >> 1;
    int q1 = ((wid + 1) * 15) >> 1;
    int acc = 0;
    for (int q = q0; q < q1; ++q) {
        int gbase = q * 4;
        float4 v[4];
        ulonglong2 w[8];
#pragma unroll
        for (int u = 0; u < 4; ++u) {
            int ia = (gbase + u) * 64 + lane;
            if (ia > N_NEU / 4 - 1) ia = N_NEU / 4 - 1; // pad groups: masked by zero words
            v[u] = row4[ia];
        }
#pragma unroll
        for (int u = 0; u < 8; ++u) w[u] = bp2[base2 + q * 8 + u];
#pragma unroll
        for (int u = 0; u < 4; ++u) {
            unsigned long long b0 = __ballot(v[u].x != 0.0f);
            unsigned long long b1 = __ballot(v[u].y != 0.0f);
            unsigned long long b2 = __ballot(v[u].z != 0.0f);
            unsigned long long b3 = __ballot(v[u].w != 0.0f);
            acc += __popcll(b0 & w[2 * u].x) + __popcll(b1 & w[2 * u].y)
                 + __popcll(b2 & w[2 * u + 1].x) + __popcll(b3 & w[2 * u + 1].y);
        }
    }
    __shared__ int sacc[4][64];
    sacc[wid][lane] = acc;
    __syncthreads();
    if (wid == 0 && lane < nc) {
        int s = sacc[0][lane] + sacc[1][lane] + sacc[2][lane] + sacc[3][lane];
        selected[myc * T_USE + t] = (float)s;
    }
}

// ---------------------------------------------------------------------------
// fano_loss: one block, 16 waves (wave = bin). Phase 1: stage the 100 KB
// `selected` into LDS with coalesced float4 loads (stride-501 padding ->
// conflict-free lane-per-class reads). Phase 2: lane c accumulates bin sums
// from LDS in double (exact). Phase 3: wave 0 does the MSE.
// ---------------------------------------------------------------------------
__global__ void __launch_bounds__(1024)
fano_loss_kernel(const float* __restrict__ selected,
                 const float* __restrict__ exp_fanos,
                 float* __restrict__ out) {
    __shared__ float lds[C_CLS * LDS_STRIDE]; // 100,200 B
    __shared__ float sf[NBINS];
    const float4* __restrict__ sel4 = (const float4*)selected;
    for (int i = threadIdx.x; i < C_CLS * T_USE / 4; i += 1024) {
        float4 v = sel4[i];
        int r = i / (T_USE / 4);
        int p = (i - r * (T_USE / 4)) * 4;
        float* dst = &lds[r * LDS_STRIDE + p];
        dst[0] = v.x; dst[1] = v.y; dst[2] = v.z; dst[3] = v.w;
    }
    __syncthreads();
    int wid = threadIdx.x >> 6;
    int lane = threadIdx.x & 63;
    int b = d_bins[wid];
    int nb = T_USE / b;
    float fano = 0.f;
    if (lane < C_CLS) {
        const float* row = &lds[lane * LDS_STRIDE];
        double s1 = 0.0, s2 = 0.0;
        for (int i = 0; i < nb; ++i) {
            float cs = 0.f;
            int base = i * b;
            for (int j = 0; j < b; ++j) cs += row[base + j];
            s1 += cs;
            s2 += (double)cs * (double)cs;
        }
        double mean = s1 / nb;
        double var = s2 / nb - mean * mean;
        if (var < 0.0) var = 0.0;
        double m = mean > EPS ? mean : EPS;
        fano = (float)(var / m);
    }
    for (int off = 32; off > 0; off >>= 1) fano += __shfl_down(fano, off);
    if (lane == 0) sf[wid] = fano / (float)C_CLS;
    __syncthreads();
    if (wid == 0) {
        float sq = 0.f;
        if (lane < NBINS) {
            float d = exp_fanos[lane] - sf[lane];
            sq = d * d;
        }
        for (int off = 32; off > 0; off >>= 1) sq += __shfl_down(sq, off);
        if (lane == 0) out[0] = 10.0f * sq / (float)NBINS;
    }
}

extern "C" void kernel_launch(void* const* d_in, const int* in_sizes, int n_in,
                              void* d_out, int out_size, void* d_ws, size_t ws_size,
                              hipStream_t stream) {
    const float* spikes    = (const float*)d_in[0];
    const float* exp_fanos = (const float*)d_in[1];
    const int*   trials    = (const int*)d_in[2];
    const void*  mask      = d_in[3];
    float* out = (float*)d_out;

    char* ws = (char*)d_ws;
    int*   flags   = (int*)(ws + 0);
    int*   ncls    = (int*)(ws + 256);
    int*   clsofb  = (int*)(ws + 512);
    unsigned long long* bits = (unsigned long long*)(ws + 8192);
    float* selected = (float*)(ws + 204800);

    init_tc_kernel<<<1, 64, 0, stream>>>(trials, flags, ncls, clsofb);
    detect_mode_kernel<<<256, 256, 0, stream>>>((const unsigned int*)mask, flags);
    build_bits_kernel<<<dim3(C_CLS, 8), 64, 0, stream>>>(mask, flags, bits);
    stream_kernel<<<B_TR * T_USE, 256, 0, stream>>>(spikes, ncls, clsofb, bits, selected);
    fano_loss_kernel<<<1, 1024, 0, stream>>>(selected, exp_fanos, out);
}